// Round 1
// baseline (63.210 us; speedup 1.0000x reference)
//
#include <hip/hip_runtime.h>

// Problem constants (from reference): x,y are [B,C,H,W] fp32
constexpr int Bn = 8, Cn = 2, Hn = 256, Wn = 4096;
constexpr long long NTOT = (long long)Bn * Cn * Hn * Wn;   // 16,777,216

__global__ void zero_ws_kernel(double* ws) {
    ws[0] = 0.0;
}

// One block per (b,c,h) row. Window is 1024 contiguous floats starting at
// clamped s = clip(mask_pos[b], 0, W - w). Round down to float4 alignment and
// predicate the boundary groups.
__global__ __launch_bounds__(256)
void masked_mse_reduce_kernel(const float* __restrict__ x,
                              const float* __restrict__ y,
                              const int* __restrict__ mask_pos,
                              const int* __restrict__ mask_width,
                              double* __restrict__ ws) {
    const int row = blockIdx.x;            // 0 .. B*C*H-1
    const int b   = row / (Cn * Hn);

    const int w    = mask_width[0];
    const int smax = Wn - w;
    int s = mask_pos[b];
    s = s < 0 ? 0 : (s > smax ? smax : s);
    const int e  = s + w;                  // exclusive end
    const int s4 = s & ~3;                 // aligned start
    const int e4 = (e + 3) & ~3;           // aligned end
    const int ngroups = (e4 - s4) >> 2;    // 256 or 257 float4 groups

    const size_t base = (size_t)row * Wn + (size_t)s4;
    const float4* __restrict__ xr = (const float4*)(x + base);
    const float4* __restrict__ yr = (const float4*)(y + base);

    float acc = 0.0f;
    for (int g = threadIdx.x; g < ngroups; g += blockDim.x) {
        const float4 xv = xr[g];
        const float4 yv = yr[g];
        const int col = s4 + (g << 2);
        const float d0 = xv.x - yv.x;
        const float d1 = xv.y - yv.y;
        const float d2 = xv.z - yv.z;
        const float d3 = xv.w - yv.w;
        if (col >= s && col + 3 < e) {
            // fully inside window (the common case)
            acc += d0 * d0 + d1 * d1 + d2 * d2 + d3 * d3;
        } else {
            if (col + 0 >= s && col + 0 < e) acc += d0 * d0;
            if (col + 1 >= s && col + 1 < e) acc += d1 * d1;
            if (col + 2 >= s && col + 2 < e) acc += d2 * d2;
            if (col + 3 >= s && col + 3 < e) acc += d3 * d3;
        }
    }

    // wave-64 butterfly reduce
    #pragma unroll
    for (int off = 32; off > 0; off >>= 1)
        acc += __shfl_down(acc, off, 64);

    __shared__ float wsum[4];
    const int lane = threadIdx.x & 63;
    const int wid  = threadIdx.x >> 6;
    if (lane == 0) wsum[wid] = acc;
    __syncthreads();

    if (threadIdx.x == 0) {
        const float bsum = wsum[0] + wsum[1] + wsum[2] + wsum[3];
        atomicAdd(ws, (double)bsum);
    }
}

__global__ void finalize_kernel(const double* __restrict__ ws,
                                float* __restrict__ out) {
    out[0] = (float)(ws[0] / (double)NTOT);
}

extern "C" void kernel_launch(void* const* d_in, const int* in_sizes, int n_in,
                              void* d_out, int out_size, void* d_ws, size_t ws_size,
                              hipStream_t stream) {
    const float* x          = (const float*)d_in[0];
    const float* y          = (const float*)d_in[1];
    const int*   mask_pos   = (const int*)d_in[2];
    const int*   mask_width = (const int*)d_in[3];
    float*       out        = (float*)d_out;
    double*      acc        = (double*)d_ws;

    zero_ws_kernel<<<1, 1, 0, stream>>>(acc);

    const int rows = Bn * Cn * Hn;   // 4096 blocks
    masked_mse_reduce_kernel<<<rows, 256, 0, stream>>>(x, y, mask_pos, mask_width, acc);

    finalize_kernel<<<1, 1, 0, stream>>>(acc, out);
}

// Round 2
// 15.288 us; speedup vs baseline: 4.1345x; 4.1345x over previous
//
#include <hip/hip_runtime.h>

// Problem constants (from reference): x,y are [B,C,H,W] fp32
constexpr int Bn = 8, Cn = 2, Hn = 256, Wn = 4096;
constexpr long long NTOT = (long long)Bn * Cn * Hn * Wn;   // 16,777,216
constexpr int ROWS = Bn * Cn * Hn;                          // 4096

// Stage 1: one block per (b,c,h) row. Window is mask_width contiguous floats
// starting at clamped s = clip(mask_pos[b], 0, W - w). Each block writes ONE
// float partial sum to partial[blockIdx.x] — no atomics anywhere.
__global__ __launch_bounds__(256)
void masked_mse_partial_kernel(const float* __restrict__ x,
                               const float* __restrict__ y,
                               const int* __restrict__ mask_pos,
                               const int* __restrict__ mask_width,
                               float* __restrict__ partial) {
    const int row = blockIdx.x;            // 0 .. ROWS-1
    const int b   = row / (Cn * Hn);

    const int w    = mask_width[0];
    const int smax = Wn - w;
    int s = mask_pos[b];
    s = s < 0 ? 0 : (s > smax ? smax : s);
    const int e  = s + w;                  // exclusive end
    const int s4 = s & ~3;                 // float4-aligned start
    const int e4 = (e + 3) & ~3;           // float4-aligned end
    const int ngroups = (e4 - s4) >> 2;    // 256 or 257 groups

    const size_t base = (size_t)row * Wn + (size_t)s4;
    const float4* __restrict__ xr = (const float4*)(x + base);
    const float4* __restrict__ yr = (const float4*)(y + base);

    float acc = 0.0f;
    for (int g = threadIdx.x; g < ngroups; g += blockDim.x) {
        const float4 xv = xr[g];
        const float4 yv = yr[g];
        const int col = s4 + (g << 2);
        const float d0 = xv.x - yv.x;
        const float d1 = xv.y - yv.y;
        const float d2 = xv.z - yv.z;
        const float d3 = xv.w - yv.w;
        if (col >= s && col + 3 < e) {
            acc += d0 * d0 + d1 * d1 + d2 * d2 + d3 * d3;
        } else {
            if (col + 0 >= s && col + 0 < e) acc += d0 * d0;
            if (col + 1 >= s && col + 1 < e) acc += d1 * d1;
            if (col + 2 >= s && col + 2 < e) acc += d2 * d2;
            if (col + 3 >= s && col + 3 < e) acc += d3 * d3;
        }
    }

    // wave-64 butterfly reduce
    #pragma unroll
    for (int off = 32; off > 0; off >>= 1)
        acc += __shfl_down(acc, off, 64);

    __shared__ float wsum[4];
    const int lane = threadIdx.x & 63;
    const int wid  = threadIdx.x >> 6;
    if (lane == 0) wsum[wid] = acc;
    __syncthreads();

    if (threadIdx.x == 0)
        partial[row] = wsum[0] + wsum[1] + wsum[2] + wsum[3];
}

// Stage 2: one block sums ROWS float partials in double, writes the mean.
__global__ __launch_bounds__(256)
void masked_mse_final_kernel(const float* __restrict__ partial,
                             float* __restrict__ out) {
    double acc = 0.0;
    for (int i = threadIdx.x; i < ROWS; i += 256)
        acc += (double)partial[i];

    #pragma unroll
    for (int off = 32; off > 0; off >>= 1)
        acc += __shfl_down(acc, off, 64);

    __shared__ double wsum[4];
    const int lane = threadIdx.x & 63;
    const int wid  = threadIdx.x >> 6;
    if (lane == 0) wsum[wid] = acc;
    __syncthreads();

    if (threadIdx.x == 0) {
        const double total = wsum[0] + wsum[1] + wsum[2] + wsum[3];
        out[0] = (float)(total / (double)NTOT);
    }
}

extern "C" void kernel_launch(void* const* d_in, const int* in_sizes, int n_in,
                              void* d_out, int out_size, void* d_ws, size_t ws_size,
                              hipStream_t stream) {
    const float* x          = (const float*)d_in[0];
    const float* y          = (const float*)d_in[1];
    const int*   mask_pos   = (const int*)d_in[2];
    const int*   mask_width = (const int*)d_in[3];
    float*       out        = (float*)d_out;
    float*       partial    = (float*)d_ws;   // ROWS floats = 16 KB scratch

    masked_mse_partial_kernel<<<ROWS, 256, 0, stream>>>(x, y, mask_pos, mask_width, partial);
    masked_mse_final_kernel<<<1, 256, 0, stream>>>(partial, out);
}

// Round 3
// 13.868 us; speedup vs baseline: 4.5579x; 1.1024x over previous
//
#include <hip/hip_runtime.h>

// Problem constants (from reference): x,y are [B,C,H,W] fp32
constexpr int Bn = 8, Cn = 2, Hn = 256, Wn = 4096;
constexpr long long NTOT = (long long)Bn * Cn * Hn * Wn;   // 16,777,216
constexpr int ROWS = Bn * Cn * Hn;                          // 4096
constexpr int RPB  = 8;                                     // rows per block
constexpr int NBLK = ROWS / RPB;                            // 512

// Stage 1: RPB rows per block. All rows in a block share the same batch b
// (RPB divides Cn*Hn), so one window computation serves all rows. For the
// fast path (w == 1024, 256 threads): thread t always covers float4 group t;
// threads 1..255 are provably fully inside [s, s+1024); thread 0 handles the
// head-excluded elements of group 0 plus the tail group's included elements
// (together exactly 4 elements). 16 independent 16B loads per thread.
__global__ __launch_bounds__(256)
void masked_mse_partial_kernel(const float* __restrict__ x,
                               const float* __restrict__ y,
                               const int* __restrict__ mask_pos,
                               const int* __restrict__ mask_width,
                               float* __restrict__ partial) {
    const int tid  = threadIdx.x;
    const int row0 = blockIdx.x * RPB;
    const int b    = row0 / (Cn * Hn);

    const int w    = mask_width[0];
    const int smax = Wn - w;
    int s = mask_pos[b];
    s = s < 0 ? 0 : (s > smax ? smax : s);
    const int e    = s + w;
    const int s4   = s & ~3;               // aligned start
    const int head = s - s4;               // 0..3

    float acc = 0.0f;

    if (w == 1024) {
        // ---- fast path: one aligned group per thread per row ----
        #pragma unroll
        for (int r = 0; r < RPB; ++r) {
            const float* __restrict__ xrow = x + (size_t)(row0 + r) * Wn + s4;
            const float* __restrict__ yrow = y + (size_t)(row0 + r) * Wn + s4;
            const float4 xv = *(const float4*)(xrow + 4 * tid);
            const float4 yv = *(const float4*)(yrow + 4 * tid);
            float d0 = xv.x - yv.x;
            float d1 = xv.y - yv.y;
            float d2 = xv.z - yv.z;
            float d3 = xv.w - yv.w;
            if (tid == 0 && head) {
                // exclude first `head` elements of group 0
                d0 = 0.0f;
                if (head > 1) d1 = 0.0f;
                if (head > 2) d2 = 0.0f;
                // include first `head` elements of the tail group
                const float4 xt = *(const float4*)(xrow + 1024);
                const float4 yt = *(const float4*)(yrow + 1024);
                const float t0 = xt.x - yt.x;
                const float t1 = xt.y - yt.y;
                const float t2 = xt.z - yt.z;
                acc += t0 * t0;
                if (head > 1) acc += t1 * t1;
                if (head > 2) acc += t2 * t2;
            }
            acc += d0 * d0 + d1 * d1 + d2 * d2 + d3 * d3;
        }
    } else {
        // ---- generic fallback (never hit in this bench) ----
        const int e4 = (e + 3) & ~3;
        const int ngroups = (e4 - s4) >> 2;
        for (int r = 0; r < RPB; ++r) {
            const float* __restrict__ xrow = x + (size_t)(row0 + r) * Wn + s4;
            const float* __restrict__ yrow = y + (size_t)(row0 + r) * Wn + s4;
            for (int g = tid; g < ngroups; g += 256) {
                const float4 xv = *(const float4*)(xrow + 4 * g);
                const float4 yv = *(const float4*)(yrow + 4 * g);
                const int col = s4 + (g << 2);
                const float d0 = xv.x - yv.x;
                const float d1 = xv.y - yv.y;
                const float d2 = xv.z - yv.z;
                const float d3 = xv.w - yv.w;
                if (col >= s && col + 3 < e) {
                    acc += d0 * d0 + d1 * d1 + d2 * d2 + d3 * d3;
                } else {
                    if (col + 0 >= s && col + 0 < e) acc += d0 * d0;
                    if (col + 1 >= s && col + 1 < e) acc += d1 * d1;
                    if (col + 2 >= s && col + 2 < e) acc += d2 * d2;
                    if (col + 3 >= s && col + 3 < e) acc += d3 * d3;
                }
            }
        }
    }

    // wave-64 butterfly reduce
    #pragma unroll
    for (int off = 32; off > 0; off >>= 1)
        acc += __shfl_down(acc, off, 64);

    __shared__ float wsum[4];
    const int lane = tid & 63;
    const int wid  = tid >> 6;
    if (lane == 0) wsum[wid] = acc;
    __syncthreads();

    if (tid == 0)
        partial[blockIdx.x] = wsum[0] + wsum[1] + wsum[2] + wsum[3];
}

// Stage 2: one block sums NBLK float partials in double, writes the mean.
__global__ __launch_bounds__(256)
void masked_mse_final_kernel(const float* __restrict__ partial,
                             float* __restrict__ out) {
    double acc = 0.0;
    for (int i = threadIdx.x; i < NBLK; i += 256)
        acc += (double)partial[i];

    #pragma unroll
    for (int off = 32; off > 0; off >>= 1)
        acc += __shfl_down(acc, off, 64);

    __shared__ double wsum[4];
    const int lane = threadIdx.x & 63;
    const int wid  = threadIdx.x >> 6;
    if (lane == 0) wsum[wid] = acc;
    __syncthreads();

    if (threadIdx.x == 0) {
        const double total = wsum[0] + wsum[1] + wsum[2] + wsum[3];
        out[0] = (float)(total / (double)NTOT);
    }
}

extern "C" void kernel_launch(void* const* d_in, const int* in_sizes, int n_in,
                              void* d_out, int out_size, void* d_ws, size_t ws_size,
                              hipStream_t stream) {
    const float* x          = (const float*)d_in[0];
    const float* y          = (const float*)d_in[1];
    const int*   mask_pos   = (const int*)d_in[2];
    const int*   mask_width = (const int*)d_in[3];
    float*       out        = (float*)d_out;
    float*       partial    = (float*)d_ws;   // NBLK floats = 2 KB scratch

    masked_mse_partial_kernel<<<NBLK, 256, 0, stream>>>(x, y, mask_pos, mask_width, partial);
    masked_mse_final_kernel<<<1, 256, 0, stream>>>(partial, out);
}

// Round 4
// 11.657 us; speedup vs baseline: 5.4225x; 1.1897x over previous
//
#include <hip/hip_runtime.h>

// Problem constants (from reference): x,y are [B,C,H,W] fp32
constexpr int Bn = 8, Cn = 2, Hn = 256, Wn = 4096;
constexpr long long NTOT = (long long)Bn * Cn * Hn * Wn;   // 16,777,216
constexpr int ROWS = Bn * Cn * Hn;                          // 4096
constexpr int RPB  = 4;                                     // rows per block
constexpr int NBLK = ROWS / RPB;                            // 1024

// Stage 1: RPB rows per block (all share the same batch b since RPB | Cn*Hn).
// Fast path (w==1024): thread t covers float4 group t of each row's aligned
// window. ALL 2*RPB loads are issued into named registers before any compute
// so the hardware has 8 independent global_load_dwordx4 in flight per thread.
// Thread 0 fixes up the head-excluded / tail-included elements (head in 0..3).
__global__ __launch_bounds__(256)
void masked_mse_partial_kernel(const float* __restrict__ x,
                               const float* __restrict__ y,
                               const int* __restrict__ mask_pos,
                               const int* __restrict__ mask_width,
                               float* __restrict__ partial) {
    const int tid  = threadIdx.x;
    const int row0 = blockIdx.x * RPB;
    const int b    = row0 / (Cn * Hn);

    const int w    = mask_width[0];
    const int smax = Wn - w;
    int s = mask_pos[b];
    s = s < 0 ? 0 : (s > smax ? smax : s);
    const int e    = s + w;
    const int s4   = s & ~3;               // aligned start
    const int head = s - s4;               // 0..3

    float acc = 0.0f;

    if (w == 1024) {
        const float* __restrict__ xp = x + (size_t)row0 * Wn + s4 + 4 * tid;
        const float* __restrict__ yp = y + (size_t)row0 * Wn + s4 + 4 * tid;

        // ---- phase 1: issue all loads (independent, static-indexed) ----
        float4 xs[RPB], ys[RPB];
        #pragma unroll
        for (int r = 0; r < RPB; ++r) {
            xs[r] = *(const float4*)(xp + (size_t)r * Wn);
            ys[r] = *(const float4*)(yp + (size_t)r * Wn);
        }

        // ---- phase 2: consume ----
        #pragma unroll
        for (int r = 0; r < RPB; ++r) {
            float d0 = xs[r].x - ys[r].x;
            float d1 = xs[r].y - ys[r].y;
            float d2 = xs[r].z - ys[r].z;
            float d3 = xs[r].w - ys[r].w;
            if (tid == 0 && head) {         // exclude pre-window elements
                d0 = 0.0f;
                if (head > 1) d1 = 0.0f;
                if (head > 2) d2 = 0.0f;
            }
            acc += d0 * d0 + d1 * d1 + d2 * d2 + d3 * d3;
        }

        // ---- head/tail correction: include first `head` elems past group 255
        if (tid == 0 && head) {
            const float* __restrict__ xt = x + (size_t)row0 * Wn + s4 + 1024;
            const float* __restrict__ yt = y + (size_t)row0 * Wn + s4 + 1024;
            #pragma unroll
            for (int r = 0; r < RPB; ++r) {
                const float4 xv = *(const float4*)(xt + (size_t)r * Wn);
                const float4 yv = *(const float4*)(yt + (size_t)r * Wn);
                const float t0 = xv.x - yv.x;
                const float t1 = xv.y - yv.y;
                const float t2 = xv.z - yv.z;
                acc += t0 * t0;
                if (head > 1) acc += t1 * t1;
                if (head > 2) acc += t2 * t2;
            }
        }
    } else {
        // ---- generic fallback (never hit in this bench) ----
        const int e4 = (e + 3) & ~3;
        const int ngroups = (e4 - s4) >> 2;
        for (int r = 0; r < RPB; ++r) {
            const float* __restrict__ xrow = x + (size_t)(row0 + r) * Wn + s4;
            const float* __restrict__ yrow = y + (size_t)(row0 + r) * Wn + s4;
            for (int g = tid; g < ngroups; g += 256) {
                const float4 xv = *(const float4*)(xrow + 4 * g);
                const float4 yv = *(const float4*)(yrow + 4 * g);
                const int col = s4 + (g << 2);
                const float d0 = xv.x - yv.x;
                const float d1 = xv.y - yv.y;
                const float d2 = xv.z - yv.z;
                const float d3 = xv.w - yv.w;
                if (col >= s && col + 3 < e) {
                    acc += d0 * d0 + d1 * d1 + d2 * d2 + d3 * d3;
                } else {
                    if (col + 0 >= s && col + 0 < e) acc += d0 * d0;
                    if (col + 1 >= s && col + 1 < e) acc += d1 * d1;
                    if (col + 2 >= s && col + 2 < e) acc += d2 * d2;
                    if (col + 3 >= s && col + 3 < e) acc += d3 * d3;
                }
            }
        }
    }

    // wave-64 butterfly reduce
    #pragma unroll
    for (int off = 32; off > 0; off >>= 1)
        acc += __shfl_down(acc, off, 64);

    __shared__ float wsum[4];
    const int lane = tid & 63;
    const int wid  = tid >> 6;
    if (lane == 0) wsum[wid] = acc;
    __syncthreads();

    if (tid == 0)
        partial[blockIdx.x] = wsum[0] + wsum[1] + wsum[2] + wsum[3];
}

// Stage 2: one block sums NBLK float partials (float4-vectorized) in double.
__global__ __launch_bounds__(256)
void masked_mse_final_kernel(const float* __restrict__ partial,
                             float* __restrict__ out) {
    const float4 v = ((const float4*)partial)[threadIdx.x];  // NBLK/4 == 256
    double acc = (double)v.x + (double)v.y + (double)v.z + (double)v.w;

    #pragma unroll
    for (int off = 32; off > 0; off >>= 1)
        acc += __shfl_down(acc, off, 64);

    __shared__ double wsum[4];
    const int lane = threadIdx.x & 63;
    const int wid  = threadIdx.x >> 6;
    if (lane == 0) wsum[wid] = acc;
    __syncthreads();

    if (threadIdx.x == 0) {
        const double total = wsum[0] + wsum[1] + wsum[2] + wsum[3];
        out[0] = (float)(total / (double)NTOT);
    }
}

extern "C" void kernel_launch(void* const* d_in, const int* in_sizes, int n_in,
                              void* d_out, int out_size, void* d_ws, size_t ws_size,
                              hipStream_t stream) {
    const float* x          = (const float*)d_in[0];
    const float* y          = (const float*)d_in[1];
    const int*   mask_pos   = (const int*)d_in[2];
    const int*   mask_width = (const int*)d_in[3];
    float*       out        = (float*)d_out;
    float*       partial    = (float*)d_ws;   // NBLK floats = 4 KB scratch

    masked_mse_partial_kernel<<<NBLK, 256, 0, stream>>>(x, y, mask_pos, mask_width, partial);
    masked_mse_final_kernel<<<1, 256, 0, stream>>>(partial, out);
}